// Round 1
// 72.515 us; speedup vs baseline: 1.0050x; 1.0050x over previous
//
#include <hip/hip_runtime.h>
#include <math.h>

#define OUT_H 7
#define OUT_W 7
#define NBINS 49
#define PAD 66                 // dword row stride: even (b64 LDS ops stay
                               // 8B-aligned) and 66%32=2 spreads banks per row
#define TSZ (64 * PAD)         // dwords per table

// v19 — two-table pyramid, full-grid residency.
// v18 (72.9us harness) = ~45us harness poison-fill + ~27us kernel. Kernel was
// latency-bound at 3 blocks/CU (53KB LDS -> 768 resident + 256 straggler
// round). v19 deletes the C2 LDS table: w in {1,2} answered from C1, w==3
// adds one exec-mask-predicated middle-column read (~15% of lanes), w>=4
// uses C4 as before. C4 is built straight from the in-register C2 (w2[]),
// with the 2-value cross-thread seam fetched via __shfl_down(.,1); the q==3
// seam writes only C4[62..63], which no valid query (x<=60) reads.
// LDS 53KB -> 36KB => 4 blocks/CU = whole 1024-block grid co-resident in one
// round; barriers 4 -> 2 (cnt-init sync merged by deferring list-append to
// the build phase). Exact integer bin bounds kept from v18 (absmax 0).
__global__ __launch_bounds__(256, 4) void roipool_v19(
    const float* __restrict__ feat, const int* __restrict__ rois, int nroi,
    float* __restrict__ out)
{
    constexpr int C = 256, H = 64, W = 64, HW = H * W;
    __shared__ float tab[2 * TSZ];          // C1 | C4   (33792 B)
    __shared__ unsigned char bh[128][8];    // absolute row bounds per roi
    __shared__ unsigned char bw[128][8];    // absolute col bounds per roi
    __shared__ unsigned char lst[128];      // rois of this batch (any order)
    __shared__ int cnt;

    const int bx = blockIdx.x;
    const int b  = bx >> 8;       // batch (4)
    const int c  = bx & 255;      // channel (256)
    const int t  = threadIdx.x;

    if (t == 0) cnt = 0;          // ordered vs phase-1 atomics by sync1

    // ---- Phase 0: stage plane -> C1 (dense float4), bounds ----
    const float* plane = feat + (size_t)(b * C + c) * HW;
    float4 v[4];
#pragma unroll
    for (int i = 0; i < 4; ++i) v[i] = ((const float4*)plane)[t + 256 * i];
#pragma unroll
    for (int i = 0; i < 4; ++i) {
        const int f = t + 256 * i;            // float4 index 0..1023
        const int row = f >> 4, c4 = f & 15;
        float* dst = &tab[row * PAD + c4 * 4];
        *(float2*)dst       = make_float2(v[i].x, v[i].y);   // b64, 8B-aligned
        *(float2*)(dst + 2) = make_float2(v[i].z, v[i].w);
    }

    bool mine = false;
    const int rr = t & 127;
    if (rr < nroi) {
        const int* rp = rois + rr * 5;
        if (t < 128) {
            const int y1 = rp[2];
            const int rh = rp[4] - y1 + 1;
#pragma unroll
            for (int k = 0; k <= 7; ++k)
                bh[rr][k] = (unsigned char)(y1 + (k * rh) / OUT_H);
            mine = (rp[0] == b);              // append deferred to phase 1
        } else {
            const int x1 = rp[1];
            const int rw = rp[3] - x1 + 1;
#pragma unroll
            for (int k = 0; k <= 7; ++k)
                bw[rr][k] = (unsigned char)(x1 + (k * rw) / OUT_W);
        }
    }
    __syncthreads();              // sync1: C1 + bounds + cnt-init ready

    // ---- Phase 1: build C4 from C1 (C2 lives in regs; shfl for the seam) --
    {
        const int row = t >> 2, q = t & 3, x0 = q * 16;
        const float* src = &tab[row * PAD + x0];
        float2 r[8];
#pragma unroll
        for (int i = 0; i < 8; ++i) r[i] = ((const float2*)src)[i];
        const float nb = tab[row * PAD + (x0 + 16 < 64 ? x0 + 16 : 63)];
        float2 w2[8];
#pragma unroll
        for (int i = 0; i < 8; ++i) {
            const float nx = (i < 7) ? r[i + 1].x : nb;
            w2[i].x = fmaxf(r[i].x, r[i].y);      // C2[x]   = max(x, x+1c)
            w2[i].y = fmaxf(r[i].y, nx);
        }
        // C2[x0+16], C2[x0+17] come from lane t+1 (same row when q<3; for
        // q==3 the result is garbage but only feeds C4[62..63], never read
        // by a valid query since xs, xs+s <= 60 for w>=4).
        const float n16 = __shfl_down(w2[0].x, 1);
        const float n17 = __shfl_down(w2[0].y, 1);
        float* dst = &tab[TSZ + row * PAD + x0];
#pragma unroll
        for (int i = 0; i < 8; ++i) {
            const float d0 = (i < 7) ? w2[i + 1].x : n16;
            const float d1 = (i < 7) ? w2[i + 1].y : n17;
            float2 u;
            u.x = fmaxf(w2[i].x, d0);             // C4[x] = max(C2[x], C2[x+2c])
            u.y = fmaxf(w2[i].y, d1);
            ((float2*)dst)[i] = u;
        }
    }
    if (mine) {                   // compaction (cnt=0 ordered by sync1)
        const int p = atomicAdd(&cnt, 1);
        lst[p] = (unsigned char)rr;
    }
    __syncthreads();              // sync2: C4 + list ready

    // ---- Phase 2: all bins of all rois of this batch, from LDS ----
    const int tot = cnt * NBINS;
    for (int g = t; g < tot; g += 256) {
        const int li  = g / NBINS;
        const int bin = g - li * NBINS;
        const int n   = lst[li];
        const int ph  = (bin * 37) >> 8;          // exact bin/7 for 0..48
        const int pw  = bin - ph * OUT_W;

        const int ys = bh[n][ph],  ye = bh[n][ph + 1];
        const int xs = bw[n][pw],  xe = bw[n][pw + 1];
        const int h = ye - ys, w = xe - xs;       // 0..7

        const bool small = (w < 4);
        const int toff = small ? 0 : TSZ;         // C1 for w<4, C4 for w>=4
        const int s    = small ? (w > 1 ? w - 1 : 0) : (w - 4);

        const int ylim = (h > 0) ? (ye - 1) : ys; // all reads stay in-image
        float m = -INFINITY;
#pragma unroll
        for (int j = 0; j < 7; ++j) {
            int yj = ys + j;
            yj = yj < ylim ? yj : ylim;           // dup rows harmless (max)
            const int a = toff + yj * PAD + xs;
            m = fmaxf(m, fmaxf(tab[a], tab[a + s]));
        }
        if (w == 3) {                             // middle col, ~15% of lanes
#pragma unroll
            for (int j = 0; j < 7; ++j) {
                int yj = ys + j;
                yj = yj < ylim ? yj : ylim;
                m = fmaxf(m, tab[yj * PAD + xs + 1]);
            }
        }
        const float res = (h > 0 && w > 0) ? m : 0.0f;
        out[(n * C + c) * NBINS + bin] = res;     // 49-contig runs per roi
    }
}

extern "C" void kernel_launch(void* const* d_in, const int* in_sizes, int n_in,
                              void* d_out, int out_size, void* d_ws, size_t ws_size,
                              hipStream_t stream) {
    const float* feat = (const float*)d_in[0];
    const int*   rois = (const int*)d_in[1];
    float*       out  = (float*)d_out;

    int nroi = in_sizes[1] / 5;        // 128
    if (nroi > 128) nroi = 128;

    roipool_v19<<<4 * 256, 256, 0, stream>>>(feat, rois, nroi, out);
}

// Round 2
// 71.129 us; speedup vs baseline: 1.0245x; 1.0195x over previous
//
#include <hip/hip_runtime.h>
#include <math.h>

#define OUT_H 7
#define OUT_W 7
#define NBINS 49
#define PAD 66                 // dword row stride: even (b64 LDS ops stay
                               // 8B-aligned) and 66%32=2 spreads banks per row
#define TSZ (64 * PAD)         // dwords per table

// v20 — lean phase-2 probe. v19 (occupancy 3->4 blocks/CU, -1 barrier,
// -1 table pass) moved dur 72.87->72.51 (noise): the kernel's build
// structure is NOT the critical path. The one thing v18/v19 share is the
// query loop: 7 unconditional row-iters x 2 LDS reads with clamp-dup rows
// (mean bin h ~3.5 -> ~45% wasted reads) plus a SECOND full 7-iter loop
// when w==3. v20: fold the w==3 middle column into the main loop as a
// predicated 3rd read, and predicate rows j>=h (exec-masked; fully-dead
// iterations skip via s_cbranch_execz). ~2x fewer phase-2 LDS ops, no
// other change. Decision probe: if dur stays ~72.5, the kernel is buried
// under the harness's fixed ~45us fill + reset dispatches -> roofline.
__global__ __launch_bounds__(256, 4) void roipool_v20(
    const float* __restrict__ feat, const int* __restrict__ rois, int nroi,
    float* __restrict__ out)
{
    constexpr int C = 256, H = 64, W = 64, HW = H * W;
    __shared__ float tab[2 * TSZ];          // C1 | C4   (33792 B)
    __shared__ unsigned char bh[128][8];    // absolute row bounds per roi
    __shared__ unsigned char bw[128][8];    // absolute col bounds per roi
    __shared__ unsigned char lst[128];      // rois of this batch (any order)
    __shared__ int cnt;

    const int bx = blockIdx.x;
    const int b  = bx >> 8;       // batch (4)
    const int c  = bx & 255;      // channel (256)
    const int t  = threadIdx.x;

    if (t == 0) cnt = 0;          // ordered vs phase-1 atomics by sync1

    // ---- Phase 0: stage plane -> C1 (dense float4), bounds ----
    const float* plane = feat + (size_t)(b * C + c) * HW;
    float4 v[4];
#pragma unroll
    for (int i = 0; i < 4; ++i) v[i] = ((const float4*)plane)[t + 256 * i];
#pragma unroll
    for (int i = 0; i < 4; ++i) {
        const int f = t + 256 * i;            // float4 index 0..1023
        const int row = f >> 4, c4 = f & 15;
        float* dst = &tab[row * PAD + c4 * 4];
        *(float2*)dst       = make_float2(v[i].x, v[i].y);   // b64, 8B-aligned
        *(float2*)(dst + 2) = make_float2(v[i].z, v[i].w);
    }

    bool mine = false;
    const int rr = t & 127;
    if (rr < nroi) {
        const int* rp = rois + rr * 5;
        if (t < 128) {
            const int y1 = rp[2];
            const int rh = rp[4] - y1 + 1;
#pragma unroll
            for (int k = 0; k <= 7; ++k)
                bh[rr][k] = (unsigned char)(y1 + (k * rh) / OUT_H);
            mine = (rp[0] == b);              // append deferred to phase 1
        } else {
            const int x1 = rp[1];
            const int rw = rp[3] - x1 + 1;
#pragma unroll
            for (int k = 0; k <= 7; ++k)
                bw[rr][k] = (unsigned char)(x1 + (k * rw) / OUT_W);
        }
    }
    __syncthreads();              // sync1: C1 + bounds + cnt-init ready

    // ---- Phase 1: build C4 from C1 (C2 lives in regs; shfl for the seam) --
    {
        const int row = t >> 2, q = t & 3, x0 = q * 16;
        const float* src = &tab[row * PAD + x0];
        float2 r[8];
#pragma unroll
        for (int i = 0; i < 8; ++i) r[i] = ((const float2*)src)[i];
        const float nb = tab[row * PAD + (x0 + 16 < 64 ? x0 + 16 : 63)];
        float2 w2[8];
#pragma unroll
        for (int i = 0; i < 8; ++i) {
            const float nx = (i < 7) ? r[i + 1].x : nb;
            w2[i].x = fmaxf(r[i].x, r[i].y);      // C2[x]   = max(x, x+1c)
            w2[i].y = fmaxf(r[i].y, nx);
        }
        // C2[x0+16], C2[x0+17] come from lane t+1 (same row when q<3; for
        // q==3 the result is garbage but only feeds C4[62..63], never read
        // by a valid query since xs, xs+s <= 60 for w>=4).
        const float n16 = __shfl_down(w2[0].x, 1);
        const float n17 = __shfl_down(w2[0].y, 1);
        float* dst = &tab[TSZ + row * PAD + x0];
#pragma unroll
        for (int i = 0; i < 8; ++i) {
            const float d0 = (i < 7) ? w2[i + 1].x : n16;
            const float d1 = (i < 7) ? w2[i + 1].y : n17;
            float2 u;
            u.x = fmaxf(w2[i].x, d0);             // C4[x] = max(C2[x], C2[x+2c])
            u.y = fmaxf(w2[i].y, d1);
            ((float2*)dst)[i] = u;
        }
    }
    if (mine) {                   // compaction (cnt=0 ordered by sync1)
        const int p = atomicAdd(&cnt, 1);
        lst[p] = (unsigned char)rr;
    }
    __syncthreads();              // sync2: C4 + list ready

    // ---- Phase 2: all bins of all rois of this batch, from LDS ----
    const int tot = cnt * NBINS;
    for (int g = t; g < tot; g += 256) {
        const int li  = g / NBINS;
        const int bin = g - li * NBINS;
        const int n   = lst[li];
        const int ph  = (bin * 37) >> 8;          // exact bin/7 for 0..48
        const int pw  = bin - ph * OUT_W;

        const int ys = bh[n][ph],  ye = bh[n][ph + 1];
        const int xs = bw[n][pw],  xe = bw[n][pw + 1];
        const int h = ye - ys, w = xe - xs;       // 0..7

        const bool small = (w < 4);
        const int toff = small ? 0 : TSZ;         // C1 for w<4, C4 for w>=4
        const int s    = small ? (w > 1 ? w - 1 : 0) : (w - 4);
        const bool w3  = (w == 3);                // predicated middle column

        float m = -INFINITY;
#pragma unroll
        for (int j = 0; j < 7; ++j) {
            const int yj = ys + j;
            if ((j == 0) | (yj < ye)) {           // j < h (j==0 always; h==0
                const int a = toff + yj * PAD + xs; // row ys in-range, res->0)
                m = fmaxf(m, fmaxf(tab[a], tab[a + s]));
                if (w3) m = fmaxf(m, tab[a + 1]);
            }
        }
        const float res = (h > 0 && w > 0) ? m : 0.0f;
        out[(n * C + c) * NBINS + bin] = res;     // 49-contig runs per roi
    }
}

extern "C" void kernel_launch(void* const* d_in, const int* in_sizes, int n_in,
                              void* d_out, int out_size, void* d_ws, size_t ws_size,
                              hipStream_t stream) {
    const float* feat = (const float*)d_in[0];
    const int*   rois = (const int*)d_in[1];
    float*       out  = (float*)d_out;

    int nroi = in_sizes[1] / 5;        // 128
    if (nroi > 128) nroi = 128;

    roipool_v20<<<4 * 256, 256, 0, stream>>>(feat, rois, nroi, out);
}